// Round 17
// baseline (2139.314 us; speedup 1.0000x reference)
//
#include <hip/hip_runtime.h>

typedef unsigned short ushort_t;
typedef unsigned int uint_t;
typedef unsigned long long ulong_t;

typedef __bf16 bf16x8 __attribute__((ext_vector_type(8)));
typedef float f32x4 __attribute__((ext_vector_type(4)));
typedef float f32x16 __attribute__((ext_vector_type(16)));
typedef unsigned short u16x4 __attribute__((ext_vector_type(4)));

#define DEV __device__ __forceinline__
#define SB() __builtin_amdgcn_sched_barrier(0)
#define WAITV(n) asm volatile("s_waitcnt vmcnt(" #n ")" ::: "memory")

// ---------- helpers ----------
DEV ushort_t f2bf(float x) {  // RNE f32 -> bf16 bits
  uint_t u = __float_as_uint(x);
  u += 0x7fffu + ((u >> 16) & 1u);
  return (ushort_t)(u >> 16);
}
DEV float bf2f(ushort_t h) { return __uint_as_float(((uint_t)h) << 16); }

DEV void gload16(ulong_t g, const void* l) {
  __builtin_amdgcn_global_load_lds(
      (__attribute__((address_space(1))) void*)g,
      (__attribute__((address_space(3))) void*)(void*)l,
      16, 0, 0);
}
DEV int nxt3(int x) { return x == 2 ? 0 : x + 1; }

// ---------- zero init (zero page + stats) ----------
__global__ void zero_k(float* __restrict__ p, int n) {
  int i = blockIdx.x * 256 + threadIdx.x;
  if (i < n) p[i] = 0.f;
}

// ---------- x: NCHW f32 -> packed [px][cb][2][32] bf16 hi/lo ----------
__global__ __launch_bounds__(256) void cvt_x_k(const float* __restrict__ X,
                                               ushort_t* __restrict__ P) {
  __shared__ float T[64][65];
  const int t = threadIdx.x;
  const int p0 = blockIdx.x * 64;  // pixel base (0..16383)
  const int c0 = blockIdx.y * 64;  // channel base
  const int b = p0 >> 12;
  const int pin0 = p0 & 4095;
#pragma unroll
  for (int it = 0; it < 4; ++it) {
    const int cl = it * 16 + (t >> 4);
    const int pl = (t & 15) * 4;
    const f32x4 v = *(const f32x4*)&X[((size_t)(b * 2048 + c0 + cl)) * 4096 + pin0 + pl];
#pragma unroll
    for (int j = 0; j < 4; ++j) T[cl][pl + j] = v[j];
  }
  __syncthreads();
#pragma unroll
  for (int it = 0; it < 4; ++it) {
    const int pl = it * 16 + (t >> 4);
    const int cl = (t & 15) * 4;
    u16x4 h, l;
#pragma unroll
    for (int j = 0; j < 4; ++j) {
      float v = T[cl + j][pl];
      ushort_t hh = f2bf(v);
      h[j] = hh;
      l[j] = f2bf(v - bf2f(hh));
    }
    const int c = c0 + cl;
    const size_t o = (size_t)(p0 + pl) * 4096 + (size_t)((c >> 5) << 6) + (c & 31);
    *(u16x4*)&P[o] = h;
    *(u16x4*)&P[o + 32] = l;
  }
}

// ---------- 3x3 weights: OIHW f32 -> fragment-major reg-load layout ----------
// idx16B = ((((cb*9 + tap)*16 + cg)*2 + dt)*2 + kk)*64 + lane,  elem = idx16*8 + e
__global__ __launch_bounds__(256) void cvt_w3n_k(const float* __restrict__ W,
                                                 ushort_t* __restrict__ P,
                                                 int I, int O) {
  const int t = threadIdx.x;
  const int o = blockIdx.y;
  const int i = blockIdx.x * 256 + t;
  const float* src = W + ((size_t)o * I + i) * 9;
  const int cb = i >> 5;
  const int kk = (i >> 4) & 1, kh = (i >> 3) & 1, e = i & 7;
  const int cg = o >> 5;
  const int lane = kh * 32 + (o & 31);
#pragma unroll
  for (int j = 0; j < 9; ++j) {
    const float v = src[j];
    const ushort_t h = f2bf(v);
    const size_t b16 = ((((size_t)(cb * 9 + j) * 16 + cg) * 2 + 0) * 2 + kk) * 64 + lane;
    P[b16 * 8 + e] = h;                          // dt=0 (hi)
    P[(b16 + 128) * 8 + e] = f2bf(v - bf2f(h));  // dt=1 (lo)
  }
}

// ---------- Wb (1x1): [O][I] f32 -> [O][cb][2][32] (legacy layout) ----------
__global__ __launch_bounds__(256) void cvt_e_k(const float* __restrict__ W,
                                               ushort_t* __restrict__ P) {
  int i = blockIdx.x * 256 + threadIdx.x;  // flat over 512*512
  float v = W[i];
  ushort_t h = f2bf(v);
  const int o = i >> 9, ic = i & 511;
  const size_t d = (size_t)o * 1024 + (size_t)((ic >> 5) << 6) + (ic & 31);
  P[d] = h;
  P[d + 32] = f2bf(v - bf2f(h));
}

// ---------- per-channel sum / sumsq over [16384][512] f32 ----------
__global__ __launch_bounds__(256) void stats_k(const float* __restrict__ X,
                                               float* __restrict__ S,
                                               float* __restrict__ Q) {
  const int t = threadIdx.x;
  const int r0 = blockIdx.x * 32;
  const int c = t * 2;
  float s0 = 0, s1 = 0, q0 = 0, q1 = 0;
  for (int r = 0; r < 32; ++r) {
    const float2 v = *(const float2*)&X[((size_t)(r0 + r)) * 512 + c];
    s0 += v.x; s1 += v.y;
    q0 += v.x * v.x; q1 += v.y * v.y;
  }
  atomicAdd(&S[c], s0); atomicAdd(&S[c + 1], s1);
  atomicAdd(&Q[c], q0); atomicAdd(&Q[c + 1], q1);
}

__global__ void bnparams_k(const float* __restrict__ S, const float* __restrict__ Q,
                           const float* __restrict__ g, const float* __restrict__ b,
                           float* __restrict__ sc, float* __restrict__ sh) {
  const int t = threadIdx.x;  // 512
  const float m = S[t] * (1.0f / 16384.0f);
  const float v = Q[t] * (1.0f / 16384.0f) - m * m;
  const float inv = rsqrtf(v + 1e-5f);
  const float s = g[t] * inv;
  sc[t] = s;
  sh[t] = b[t] - m * s;
}

// ---------- BN + ReLU + split -> packed [px][cb][2][32] ----------
__global__ __launch_bounds__(256) void bnact_k(const float* __restrict__ X,
                                               const float* __restrict__ sc,
                                               const float* __restrict__ sh,
                                               ushort_t* __restrict__ P) {
  const size_t i0 = ((size_t)blockIdx.x * 256 + threadIdx.x) * 16;
  const int c0 = (int)(i0 & 511);
  const size_t px = i0 >> 9;
#pragma unroll
  for (int q = 0; q < 4; ++q) {
    const f32x4 v = *(const f32x4*)&X[i0 + q * 4];
    const f32x4 s = *(const f32x4*)&sc[c0 + q * 4];
    const f32x4 d = *(const f32x4*)&sh[c0 + q * 4];
    u16x4 h, l;
#pragma unroll
    for (int j = 0; j < 4; ++j) {
      float y = fmaf(v[j], s[j], d[j]);
      y = fmaxf(y, 0.f);
      ushort_t hh = f2bf(y);
      h[j] = hh;
      l[j] = f2bf(y - bf2f(hh));
    }
    const int c = c0 + q * 4;
    const size_t o = px * 1024 + (size_t)((c >> 5) << 6) + (c & 31);
    *(u16x4*)&P[o] = h;
    *(u16x4*)&P[o + 32] = l;
  }
}

// ---------- BN + ReLU + NHWC->NCHW fp32 (first output) ----------
__global__ __launch_bounds__(256) void bn_nchw_k(const float* __restrict__ X,
                                                 const float* __restrict__ sc,
                                                 const float* __restrict__ sh,
                                                 float* __restrict__ O) {
  __shared__ float T[64][65];
  const int t = threadIdx.x;
  const int p0 = blockIdx.x * 64;
  const int c0 = blockIdx.y * 64;
  const int b = p0 >> 12, pin0 = p0 & 4095;
#pragma unroll
  for (int it = 0; it < 4; ++it) {
    const int pl = it * 16 + (t >> 4);
    const int cl = (t & 15) * 4;
    const f32x4 v = *(const f32x4*)&X[((size_t)(p0 + pl)) * 512 + c0 + cl];
#pragma unroll
    for (int j = 0; j < 4; ++j) {
      float y = fmaf(v[j], sc[c0 + cl + j], sh[c0 + cl + j]);
      T[pl][cl + j] = fmaxf(y, 0.f);
    }
  }
  __syncthreads();
#pragma unroll
  for (int it = 0; it < 4; ++it) {
    const int cl = it * 16 + (t >> 4);
    const int pl = (t & 15) * 4;
    f32x4 o;
#pragma unroll
    for (int j = 0; j < 4; ++j) o[j] = T[pl + j][cl];
    *(f32x4*)&O[((size_t)(b * 512 + c0 + cl)) * 4096 + pin0 + pl] = o;
  }
}

// ---------- 1x1 classifier ----------
__global__ __launch_bounds__(256) void conv4_k(const float* __restrict__ X,
                                               const float* __restrict__ sc,
                                               const float* __restrict__ sh,
                                               const float* __restrict__ W4,
                                               const float* __restrict__ B4,
                                               float* __restrict__ O) {
  __shared__ float A[256][69];
  __shared__ float WL[64][19];
  const int t = threadIdx.x;
  const int g0 = blockIdx.x * 256;
  float acc[19];
#pragma unroll
  for (int n = 0; n < 19; ++n) acc[n] = 0.f;
  for (int kc = 0; kc < 8; ++kc) {
    const int k0 = kc * 64;
    __syncthreads();
#pragma unroll
    for (int it = 0; it < 16; ++it) {
      const int rl = it * 16 + (t >> 4);
      const int cl = (t & 15) * 4;
      const f32x4 v = *(const f32x4*)&X[((size_t)(g0 + rl)) * 512 + k0 + cl];
#pragma unroll
      for (int j = 0; j < 4; ++j)
        A[rl][cl + j] = fmaxf(fmaf(v[j], sc[k0 + cl + j], sh[k0 + cl + j]), 0.f);
    }
    for (int e = t; e < 1216; e += 256) {
      int k = e / 19, n = e - k * 19;
      WL[k][n] = W4[(size_t)n * 512 + k0 + k];
    }
    __syncthreads();
#pragma unroll 8
    for (int k = 0; k < 64; ++k) {
      const float a = A[t][k];
#pragma unroll
      for (int n = 0; n < 19; ++n) acc[n] = fmaf(a, WL[k][n], acc[n]);
    }
  }
  const int g = g0 + t;
  const int b = g >> 12, pin = g & 4095;
#pragma unroll
  for (int n = 0; n < 19; ++n)
    O[((size_t)(b * 19 + n)) * 4096 + pin] = acc[n] + B4[n];
}

// ---------- 3x3 conv, 16-wave / 4-waves-per-SIMD occupancy variant ----------
// 1024 threads = 16 waves (4M x 4N), wave tile 64x32 = 2x1 frags of 32x32.
// Per-wave regs: 32 acc + 32 A-frag + 16 B-frag + addr ~= 110; forced <=128
// via __launch_bounds__(1024,4) -> 4 waves/SIMD, cross-wave pipe overlap.
// A in LDS (2x48KB dbuf, tap-reuse); B via global->register (cvt_w3n layout).
// A operand: row=lane&31, k=(lane>>5)*8+e. C/D: col=lane&31,
// row=(reg&3)+8*(reg>>2)+4*(lane>>5)  [m74/m101; validated by R8-R16 absmax].
template <int AINIT>
__global__ __launch_bounds__(1024, 4) void conv9w_k(
    const ushort_t* __restrict__ A1, int S1,
    const ushort_t* __restrict__ WB, int CBt, int cbOff,
    const ushort_t* __restrict__ zp,
    float* __restrict__ Co) {
  constexpr int RW = 6;
  constexpr int SPD = 24;          // 1KB slots per dt plane
  constexpr int AI = 3;            // A-stage gloads per wave per cs (48/16)
  constexpr int APL = 24576;
  constexpr int ABUF = 49152;
  __shared__ char Ald[2 * ABUF];   // 96KB, A only
  const int t = threadIdx.x, lane = t & 63, wid = t >> 6;  // wid 0..15
  const int wr = wid >> 2;   // 0..3 (M, 64-px rows)
  const int wcn = wid & 3;   // 0..3 (N, 32-cout cols)
  const int gid = blockIdx.x, xcd = gid & 7, k_ = gid >> 3;
  const int by = xcd * 8 + (k_ & 7), bx = k_ >> 3;  // by 0..63, bx 0..3
  const int b = by >> 4, r0 = (by & 15) * 4, bbase = b * 4096;
  const int pxl = lane & 31;
  const int khalf = lane >> 5;
  const int lofs = lane * 16;
  const int row0 = by * 256 + wr * 64;
  const int col0 = bx * 128 + wcn * 32;
  const int rb = 4 * khalf;
  const int cg = bx * 4 + wcn;  // B cout-group for this wave

  auto stageAslice = [&](int cb, int bufA, int i) {
    const int g = wid * AI + i;  // 0..47
    const int d = g / SPD, rem = g - d * SPD;
    const int pxb = rem >> 1, kk = rem & 1;
    const int p = pxb * 32 + pxl;
    const int irow = r0 + (p >> 6) - 1;
    const int gpx = bbase + irow * 64 + (p & 63);
    const ulong_t el = (ulong_t)gpx * (uint_t)S1 +
                       (uint_t)(cb * 64 + d * 32 + (kk * 2 + khalf) * 8);
    const bool oob = (unsigned)irow >= 64u;
    const ulong_t src = oob ? (ulong_t)(zp + lane * 8) : (ulong_t)(A1 + el);
    gload16(src, Ald + bufA + d * APL + (pxb * 2 + kk) * 1024);
  };

  struct BS { bf16x8 b[2][2]; };  // [kk][dt]
  auto loadB = [&](BS& s, int cs, int tap) {
#pragma unroll
    for (int kk = 0; kk < 2; ++kk)
#pragma unroll
      for (int dt = 0; dt < 2; ++dt) {
        const size_t b16 =
            ((((size_t)((cs + cbOff) * 9 + tap) * 16 + cg) * 2 + dt) * 2 + kk) * 64 + lane;
        s.b[kk][dt] = *(const bf16x8*)(WB + b16 * 8);
      }
  };

  f32x16 acc[2];
  if constexpr (AINIT) {
#pragma unroll
    for (int mi = 0; mi < 2; ++mi) {
      const int c = col0 + pxl;
#pragma unroll
      for (int rg = 0; rg < 16; ++rg) {
        const int r = row0 + mi * 32 + (rg & 3) + 8 * (rg >> 2) + rb;
        acc[mi][rg] = Co[(size_t)r * 512 + c];
      }
    }
  } else {
    acc[0] = (f32x16){0.f};
    acc[1] = (f32x16){0.f};
  }

  // prologue: stage A(cs=0) into buf0
#pragma unroll
  for (int i = 0; i < AI; ++i) stageAslice(0, 0, i);
  WAITV(0);
  SB();
  __builtin_amdgcn_s_barrier();
  SB();

  for (int cs = 0; cs < CBt; ++cs) {
    const int ab = (cs & 1) * ABUF;
    const int nb = ((cs + 1) & 1) * ABUF;
#pragma unroll
    for (int tap = 0; tap < 9; ++tap) {
      BS wa;
      loadB(wa, cs, tap);  // issue early: latency hides under A ds_reads
      if (tap < AI && cs + 1 < CBt) stageAslice(cs + 1, nb, tap);
      const int prow = wr + tap / 3, dx = tap % 3 - 1;
      const char* Ab = Ald + ab;
      bf16x8 a[2][2][2];  // [mi][kk][dt]
#pragma unroll
      for (int mi = 0; mi < 2; ++mi) {
        const int pb0 = prow * 2 + mi;
        int ao0;
        if (dx == 0) {
          ao0 = pb0 * 2048 + lofs;
        } else {
          int px = pb0 * 32 + pxl + dx;
          px = px < 0 ? 0 : (px > RW * 64 - 1 ? RW * 64 - 1 : px);  // masked lanes only
          ao0 = (px >> 5) * 2048 + khalf * 512 + (px & 31) * 16;
        }
#pragma unroll
        for (int kk = 0; kk < 2; ++kk) {
          const int ao = ao0 + kk * 1024;
          a[mi][kk][0] = *(const bf16x8*)(Ab + ao);
          a[mi][kk][1] = *(const bf16x8*)(Ab + APL + ao);
        }
      }
      if (dx == -1 && pxl == 0) {
        bf16x8 z = {};
        a[0][0][0] = z; a[0][0][1] = z; a[0][1][0] = z; a[0][1][1] = z;
      }
      if (dx == 1 && pxl == 31) {
        bf16x8 z = {};
        a[1][0][0] = z; a[1][0][1] = z; a[1][1][0] = z; a[1][1][1] = z;
      }
      __builtin_amdgcn_s_setprio(1);
#pragma unroll
      for (int kk = 0; kk < 2; ++kk) {
#pragma unroll
        for (int mi = 0; mi < 2; ++mi)
          acc[mi] = __builtin_amdgcn_mfma_f32_32x32x16_bf16(
              a[mi][kk][0], wa.b[kk][0], acc[mi], 0, 0, 0);
#pragma unroll
        for (int mi = 0; mi < 2; ++mi)
          acc[mi] = __builtin_amdgcn_mfma_f32_32x32x16_bf16(
              a[mi][kk][0], wa.b[kk][1], acc[mi], 0, 0, 0);
#pragma unroll
        for (int mi = 0; mi < 2; ++mi)
          acc[mi] = __builtin_amdgcn_mfma_f32_32x32x16_bf16(
              a[mi][kk][1], wa.b[kk][0], acc[mi], 0, 0, 0);
      }
      __builtin_amdgcn_s_setprio(0);
    }
    WAITV(0);
    SB();
    __builtin_amdgcn_s_barrier();
    SB();
  }

  // epilogue: C/D col=lane&31, row=(reg&3)+8*(reg>>2)+4*(lane>>5)
#pragma unroll
  for (int mi = 0; mi < 2; ++mi) {
    const int c = col0 + pxl;
#pragma unroll
    for (int rg = 0; rg < 16; ++rg) {
      const int r = row0 + mi * 32 + (rg & 3) + 8 * (rg >> 2) + rb;
      Co[(size_t)r * 512 + c] = acc[mi][rg];
    }
  }
}

// ---------- 1x1 conv (convb): legacy LDS-B path, EPI=bias+pack ----------
__global__ __launch_bounds__(512, 2) void conv1x1_k(
    const ushort_t* __restrict__ A1, int S1,
    const ushort_t* __restrict__ WB, int CBt, int NBS,
    const ushort_t* __restrict__ zp,
    ushort_t* __restrict__ Cp, const float* __restrict__ bias) {
  constexpr int SPD = 16;
  constexpr int AI = 4;
  constexpr int APL = 16384;
  constexpr int ABUF = 32768;
  __shared__ char lds_all[147456];
  char* Ald = lds_all;
  char* Bld = lds_all + 98304;
  const int t = threadIdx.x, lane = t & 63, wid = t >> 6;
  const int wr = wid >> 1, wc = wid & 1;
  const int gid = blockIdx.x, xcd = gid & 7, k_ = gid >> 3;
  const int by = xcd * 8 + (k_ & 7), bx = k_ >> 3;
  const int b = by >> 4, r0 = (by & 15) * 4, bbase = b * 4096;
  const int pxl = lane & 31;
  const int khalf = lane >> 5;
  const int lofs = lane * 16;

  auto stageA = [&](int cb, int bufA) {
#pragma unroll
    for (int i = 0; i < AI; ++i) {
      const int g = wid * AI + i;
      const int d = g / SPD, rem = g - d * SPD;
      const int pxb = rem >> 1, kk = rem & 1;
      const int p = pxb * 32 + pxl;
      const int irow = r0 + (p >> 6);
      const int gpx = bbase + irow * 64 + (p & 63);
      const ulong_t el = (ulong_t)gpx * (uint_t)S1 +
                         (uint_t)(cb * 64 + d * 32 + (kk * 2 + khalf) * 8);
      gload16((ulong_t)(A1 + el), Ald + bufA + d * APL + (pxb * 2 + kk) * 1024);
    }
  };
  auto stageB = [&](int cb, int bufB) {
#pragma unroll
    for (int q = 0; q < 2; ++q) {
      const int s = wid * 2 + q;
      const int d = s >> 3, rem = s & 7, cob = rem >> 1, kk = rem & 1;
      const int co = bx * 128 + cob * 32 + pxl;
      const ulong_t el = (ulong_t)co * (uint_t)NBS +
                         (uint_t)(cb * 64 + d * 32 + (kk * 2 + khalf) * 8);
      gload16((ulong_t)(WB + el), Bld + bufB + d * 8192 + (cob * 2 + kk) * 1024);
    }
  };

  f32x16 acc[2][2];
#pragma unroll
  for (int i = 0; i < 2; ++i)
#pragma unroll
    for (int j2 = 0; j2 < 2; ++j2) acc[i][j2] = (f32x16){0.f};

  auto compute = [&](int abufB, int bbufB) {
    const char* Ab = Ald + abufB;
    const char* Bb = Bld + bbufB;
    bf16x8 a[2][2][2], bf[2][2][2];
#pragma unroll
    for (int ni = 0; ni < 2; ++ni)
#pragma unroll
      for (int kk = 0; kk < 2; ++kk) {
        const int bo = (wc * 2 + ni) * 2048 + kk * 1024 + lofs;
        bf[ni][kk][0] = *(const bf16x8*)(Bb + bo);
        bf[ni][kk][1] = *(const bf16x8*)(Bb + 8192 + bo);
      }
#pragma unroll
    for (int mi = 0; mi < 2; ++mi) {
      const int ao0 = ((wr * 2 + mi)) * 2048 + lofs;
#pragma unroll
      for (int kk = 0; kk < 2; ++kk) {
        const int ao = ao0 + kk * 1024;
        a[mi][kk][0] = *(const bf16x8*)(Ab + ao);
        a[mi][kk][1] = *(const bf16x8*)(Ab + APL + ao);
      }
    }
#pragma unroll
    for (int kk = 0; kk < 2; ++kk) {
#pragma unroll
      for (int mi = 0; mi < 2; ++mi)
#pragma unroll
        for (int ni = 0; ni < 2; ++ni)
          acc[mi][ni] = __builtin_amdgcn_mfma_f32_32x32x16_bf16(
              a[mi][kk][0], bf[ni][kk][0], acc[mi][ni], 0, 0, 0);
#pragma unroll
      for (int mi = 0; mi < 2; ++mi)
#pragma unroll
        for (int ni = 0; ni < 2; ++ni)
          acc[mi][ni] = __builtin_amdgcn_mfma_f32_32x32x16_bf16(
              a[mi][kk][0], bf[ni][kk][1], acc[mi][ni], 0, 0, 0);
#pragma unroll
      for (int mi = 0; mi < 2; ++mi)
#pragma unroll
        for (int ni = 0; ni < 2; ++ni)
          acc[mi][ni] = __builtin_amdgcn_mfma_f32_32x32x16_bf16(
              a[mi][kk][1], bf[ni][kk][0], acc[mi][ni], 0, 0, 0);
    }
  };

  int rr = 0;
  stageA(0, 0);
  stageB(0, 0);
  SB();
  stageA(1, ABUF);
  stageB(1, 16384);
  for (int cs = 0; cs < CBt; ++cs) {
    SB();
    WAITV(6);
    SB();
    __builtin_amdgcn_s_barrier();
    SB();
    const int rr2 = nxt3(nxt3(rr));
    if (cs + 2 < CBt) {
      stageA(cs + 2, rr2 * ABUF);
      stageB(cs + 2, rr2 * 16384);
    }
    compute(rr * ABUF, rr * 16384);
    rr = nxt3(rr);
  }

  const int row0 = by * 256 + wr * 64;
  const int col0 = bx * 128 + wc * 64;
  const int rb = 4 * khalf;
#pragma unroll
  for (int ni = 0; ni < 2; ++ni) {
    const int c = col0 + ni * 32 + pxl;
    const float bv = bias[c];
    const size_t cg2 = (size_t)((c >> 5) << 6) + (c & 31);
#pragma unroll
    for (int mi = 0; mi < 2; ++mi)
#pragma unroll
      for (int rg = 0; rg < 16; ++rg) {
        const int r = row0 + mi * 32 + (rg & 3) + 8 * (rg >> 2) + rb;
        const float v = acc[mi][ni][rg] + bv;
        const ushort_t h = f2bf(v);
        Cp[(size_t)r * 1024 + cg2] = h;
        Cp[(size_t)r * 1024 + cg2 + 32] = f2bf(v - bf2f(h));
      }
  }
}

// ---------- host ----------
extern "C" void kernel_launch(void* const* d_in, const int* in_sizes, int n_in,
                              void* d_out, int out_size, void* d_ws, size_t ws_size,
                              hipStream_t stream) {
  const float* x  = (const float*)d_in[0];
  const float* Wa = (const float*)d_in[1];
  const float* ga = (const float*)d_in[2];
  const float* ba = (const float*)d_in[3];
  const float* Wb = (const float*)d_in[4];
  const float* bb = (const float*)d_in[5];
  const float* W1 = (const float*)d_in[6];
  const float* g1 = (const float*)d_in[7];
  const float* b1 = (const float*)d_in[8];
  const float* W4 = (const float*)d_in[9];
  const float* b4 = (const float*)d_in[10];
  float* out0 = (float*)d_out;
  float* outF = out0 + (size_t)4 * 512 * 64 * 64;

  char* ws = (char*)d_ws;
  size_t off = 0;
  auto take = [&](size_t bytes) -> char* {
    char* p = ws + off;
    off += (bytes + 255) & ~(size_t)255;
    return p;
  };
  const size_t PAD = 16384;
  ushort_t* zp  = (ushort_t*)take(8192);
  float* sumA = (float*)take(2048);
  float* ssA  = (float*)take(2048);
  float* scA  = (float*)take(2048);
  float* shA  = (float*)take(2048);
  float* sum1 = (float*)take(2048);
  float* ss1  = (float*)take(2048);
  float* sc1  = (float*)take(2048);
  float* sh1  = (float*)take(2048);
  ushort_t* X2  = (ushort_t*)take((size_t)16384 * 4096 * 2 + PAD);
  ushort_t* WA2 = (ushort_t*)take((size_t)9 * 512 * 4096 * 2 + PAD);
  ushort_t* W12 = (ushort_t*)take((size_t)9 * 512 * 5120 * 2 + PAD);
  ushort_t* WBb = (ushort_t*)take((size_t)512 * 1024 * 2 + PAD);
  ushort_t* oA2 = (ushort_t*)take((size_t)16384 * 1024 * 2 + PAD);
  ushort_t* oB2 = (ushort_t*)take((size_t)16384 * 1024 * 2 + PAD);
  float* convaRaw = (float*)take((size_t)16384 * 512 * 4);
  float* conv1Raw = (float*)take((size_t)16384 * 512 * 4);
  if (ws_size < off) return;

  zero_k<<<dim3(24), dim3(256), 0, stream>>>((float*)ws, 6144);
  cvt_x_k<<<dim3(256, 32), dim3(256), 0, stream>>>(x, X2);
  cvt_w3n_k<<<dim3(8, 512), dim3(256), 0, stream>>>(Wa, WA2, 2048, 512);
  cvt_w3n_k<<<dim3(10, 512), dim3(256), 0, stream>>>(W1, W12, 2560, 512);
  cvt_e_k<<<dim3(1024), dim3(256), 0, stream>>>(Wb, WBb);

  // conva: 3x3 over x (16-wave occupancy kernel)
  conv9w_k<0><<<dim3(256), dim3(1024), 0, stream>>>(
      X2, 4096, WA2, 64, 0, zp, convaRaw);

  // conv1a: 3x3 over x-channels (cb 0..63 of W12)
  conv9w_k<0><<<dim3(256), dim3(1024), 0, stream>>>(
      X2, 4096, W12, 64, 0, zp, conv1Raw);

  stats_k<<<dim3(512), dim3(256), 0, stream>>>(convaRaw, sumA, ssA);
  bnparams_k<<<dim3(1), dim3(512), 0, stream>>>(sumA, ssA, ga, ba, scA, shA);
  bnact_k<<<dim3(2048), dim3(256), 0, stream>>>(convaRaw, scA, shA, oA2);

  // convb: 1x1 + bias, packed bf16 hi/lo out
  conv1x1_k<<<dim3(256), dim3(512), 0, stream>>>(
      oA2, 1024, WBb, 16, 1024, zp, oB2, bb);

  // conv1b: 3x3 over oB channels (cb 64..79 of W12), accumulate into conv1Raw
  conv9w_k<1><<<dim3(256), dim3(1024), 0, stream>>>(
      oB2, 1024, W12, 16, 64, zp, conv1Raw);

  stats_k<<<dim3(512), dim3(256), 0, stream>>>(conv1Raw, sum1, ss1);
  bnparams_k<<<dim3(1), dim3(512), 0, stream>>>(sum1, ss1, g1, b1, sc1, sh1);

  bn_nchw_k<<<dim3(256, 8), dim3(256), 0, stream>>>(conv1Raw, sc1, sh1, out0);
  conv4_k<<<dim3(64), dim3(256), 0, stream>>>(conv1Raw, sc1, sh1, W4, b4, outF);
}

// Round 18
// 1620.992 us; speedup vs baseline: 1.3198x; 1.3198x over previous
//
#include <hip/hip_runtime.h>

typedef unsigned short ushort_t;
typedef unsigned int uint_t;
typedef unsigned long long ulong_t;

typedef __bf16 bf16x8 __attribute__((ext_vector_type(8)));
typedef float f32x4 __attribute__((ext_vector_type(4)));
typedef float f32x16 __attribute__((ext_vector_type(16)));
typedef unsigned short u16x4 __attribute__((ext_vector_type(4)));

#define DEV __device__ __forceinline__
#define SB() __builtin_amdgcn_sched_barrier(0)
#define WAITV(n) asm volatile("s_waitcnt vmcnt(" #n ")" ::: "memory")

// ---------- helpers ----------
DEV ushort_t f2bf(float x) {  // RNE f32 -> bf16 bits
  uint_t u = __float_as_uint(x);
  u += 0x7fffu + ((u >> 16) & 1u);
  return (ushort_t)(u >> 16);
}
DEV float bf2f(ushort_t h) { return __uint_as_float(((uint_t)h) << 16); }

DEV void gload16(ulong_t g, const void* l) {
  __builtin_amdgcn_global_load_lds(
      (__attribute__((address_space(1))) void*)g,
      (__attribute__((address_space(3))) void*)(void*)l,
      16, 0, 0);
}
DEV int nxt3(int x) { return x == 2 ? 0 : x + 1; }

// ---------- zero init (zero page + stats) ----------
__global__ void zero_k(float* __restrict__ p, int n) {
  int i = blockIdx.x * 256 + threadIdx.x;
  if (i < n) p[i] = 0.f;
}

// ---------- x: NCHW f32 -> [px][2048] bf16 HI ONLY ----------
__global__ __launch_bounds__(256) void cvt_x2_k(const float* __restrict__ X,
                                                ushort_t* __restrict__ P) {
  __shared__ float T[64][65];
  const int t = threadIdx.x;
  const int p0 = blockIdx.x * 64;
  const int c0 = blockIdx.y * 64;
  const int b = p0 >> 12;
  const int pin0 = p0 & 4095;
#pragma unroll
  for (int it = 0; it < 4; ++it) {
    const int cl = it * 16 + (t >> 4);
    const int pl = (t & 15) * 4;
    const f32x4 v = *(const f32x4*)&X[((size_t)(b * 2048 + c0 + cl)) * 4096 + pin0 + pl];
#pragma unroll
    for (int j = 0; j < 4; ++j) T[cl][pl + j] = v[j];
  }
  __syncthreads();
#pragma unroll
  for (int it = 0; it < 4; ++it) {
    const int pl = it * 16 + (t >> 4);
    const int cl = (t & 15) * 4;
    u16x4 h;
#pragma unroll
    for (int j = 0; j < 4; ++j) h[j] = f2bf(T[cl + j][pl]);
    *(u16x4*)&P[(size_t)(p0 + pl) * 2048 + c0 + cl] = h;
  }
}

// ---------- 3x3 weights: OIHW f32 -> fragment-major reg-load layout ----------
// idx16B = ((((cb*9 + tap)*16 + cg)*2 + dt)*2 + kk)*64 + lane,  elem = idx16*8 + e
__global__ __launch_bounds__(256) void cvt_w3n_k(const float* __restrict__ W,
                                                 ushort_t* __restrict__ P,
                                                 int I, int O) {
  const int t = threadIdx.x;
  const int o = blockIdx.y;
  const int i = blockIdx.x * 256 + t;
  const float* src = W + ((size_t)o * I + i) * 9;
  const int cb = i >> 5;
  const int kk = (i >> 4) & 1, kh = (i >> 3) & 1, e = i & 7;
  const int cg = o >> 5;
  const int lane = kh * 32 + (o & 31);
#pragma unroll
  for (int j = 0; j < 9; ++j) {
    const float v = src[j];
    const ushort_t h = f2bf(v);
    const size_t b16 = ((((size_t)(cb * 9 + j) * 16 + cg) * 2 + 0) * 2 + kk) * 64 + lane;
    P[b16 * 8 + e] = h;                          // dt=0 (hi)
    P[(b16 + 128) * 8 + e] = f2bf(v - bf2f(h));  // dt=1 (lo)
  }
}

// ---------- Wb (1x1): [O][I] f32 -> [O][cb][2][32] (legacy layout) ----------
__global__ __launch_bounds__(256) void cvt_e_k(const float* __restrict__ W,
                                               ushort_t* __restrict__ P) {
  int i = blockIdx.x * 256 + threadIdx.x;  // flat over 512*512
  float v = W[i];
  ushort_t h = f2bf(v);
  const int o = i >> 9, ic = i & 511;
  const size_t d = (size_t)o * 1024 + (size_t)((ic >> 5) << 6) + (ic & 31);
  P[d] = h;
  P[d + 32] = f2bf(v - bf2f(h));
}

// ---------- per-channel sum / sumsq over [16384][512] f32 ----------
__global__ __launch_bounds__(256) void stats_k(const float* __restrict__ X,
                                               float* __restrict__ S,
                                               float* __restrict__ Q) {
  const int t = threadIdx.x;
  const int r0 = blockIdx.x * 32;
  const int c = t * 2;
  float s0 = 0, s1 = 0, q0 = 0, q1 = 0;
  for (int r = 0; r < 32; ++r) {
    const float2 v = *(const float2*)&X[((size_t)(r0 + r)) * 512 + c];
    s0 += v.x; s1 += v.y;
    q0 += v.x * v.x; q1 += v.y * v.y;
  }
  atomicAdd(&S[c], s0); atomicAdd(&S[c + 1], s1);
  atomicAdd(&Q[c], q0); atomicAdd(&Q[c + 1], q1);
}

__global__ void bnparams_k(const float* __restrict__ S, const float* __restrict__ Q,
                           const float* __restrict__ g, const float* __restrict__ b,
                           float* __restrict__ sc, float* __restrict__ sh) {
  const int t = threadIdx.x;  // 512
  const float m = S[t] * (1.0f / 16384.0f);
  const float v = Q[t] * (1.0f / 16384.0f) - m * m;
  const float inv = rsqrtf(v + 1e-5f);
  const float s = g[t] * inv;
  sc[t] = s;
  sh[t] = b[t] - m * s;
}

// ---------- BN + ReLU + split -> packed [px][cb][2][32] ----------
__global__ __launch_bounds__(256) void bnact_k(const float* __restrict__ X,
                                               const float* __restrict__ sc,
                                               const float* __restrict__ sh,
                                               ushort_t* __restrict__ P) {
  const size_t i0 = ((size_t)blockIdx.x * 256 + threadIdx.x) * 16;
  const int c0 = (int)(i0 & 511);
  const size_t px = i0 >> 9;
#pragma unroll
  for (int q = 0; q < 4; ++q) {
    const f32x4 v = *(const f32x4*)&X[i0 + q * 4];
    const f32x4 s = *(const f32x4*)&sc[c0 + q * 4];
    const f32x4 d = *(const f32x4*)&sh[c0 + q * 4];
    u16x4 h, l;
#pragma unroll
    for (int j = 0; j < 4; ++j) {
      float y = fmaf(v[j], s[j], d[j]);
      y = fmaxf(y, 0.f);
      ushort_t hh = f2bf(y);
      h[j] = hh;
      l[j] = f2bf(y - bf2f(hh));
    }
    const int c = c0 + q * 4;
    const size_t o = px * 1024 + (size_t)((c >> 5) << 6) + (c & 31);
    *(u16x4*)&P[o] = h;
    *(u16x4*)&P[o + 32] = l;
  }
}

// ---------- BN + ReLU + NHWC->NCHW fp32 (first output) ----------
__global__ __launch_bounds__(256) void bn_nchw_k(const float* __restrict__ X,
                                                 const float* __restrict__ sc,
                                                 const float* __restrict__ sh,
                                                 float* __restrict__ O) {
  __shared__ float T[64][65];
  const int t = threadIdx.x;
  const int p0 = blockIdx.x * 64;
  const int c0 = blockIdx.y * 64;
  const int b = p0 >> 12, pin0 = p0 & 4095;
#pragma unroll
  for (int it = 0; it < 4; ++it) {
    const int pl = it * 16 + (t >> 4);
    const int cl = (t & 15) * 4;
    const f32x4 v = *(const f32x4*)&X[((size_t)(p0 + pl)) * 512 + c0 + cl];
#pragma unroll
    for (int j = 0; j < 4; ++j) {
      float y = fmaf(v[j], sc[c0 + cl + j], sh[c0 + cl + j]);
      T[pl][cl + j] = fmaxf(y, 0.f);
    }
  }
  __syncthreads();
#pragma unroll
  for (int it = 0; it < 4; ++it) {
    const int cl = it * 16 + (t >> 4);
    const int pl = (t & 15) * 4;
    f32x4 o;
#pragma unroll
    for (int j = 0; j < 4; ++j) o[j] = T[pl + j][cl];
    *(f32x4*)&O[((size_t)(b * 512 + c0 + cl)) * 4096 + pin0 + pl] = o;
  }
}

// ---------- 1x1 classifier ----------
__global__ __launch_bounds__(256) void conv4_k(const float* __restrict__ X,
                                               const float* __restrict__ sc,
                                               const float* __restrict__ sh,
                                               const float* __restrict__ W4,
                                               const float* __restrict__ B4,
                                               float* __restrict__ O) {
  __shared__ float A[256][69];
  __shared__ float WL[64][19];
  const int t = threadIdx.x;
  const int g0 = blockIdx.x * 256;
  float acc[19];
#pragma unroll
  for (int n = 0; n < 19; ++n) acc[n] = 0.f;
  for (int kc = 0; kc < 8; ++kc) {
    const int k0 = kc * 64;
    __syncthreads();
#pragma unroll
    for (int it = 0; it < 16; ++it) {
      const int rl = it * 16 + (t >> 4);
      const int cl = (t & 15) * 4;
      const f32x4 v = *(const f32x4*)&X[((size_t)(g0 + rl)) * 512 + k0 + cl];
#pragma unroll
      for (int j = 0; j < 4; ++j)
        A[rl][cl + j] = fmaxf(fmaf(v[j], sc[k0 + cl + j], sh[k0 + cl + j]), 0.f);
    }
    for (int e = t; e < 1216; e += 256) {
      int k = e / 19, n = e - k * 19;
      WL[k][n] = W4[(size_t)n * 512 + k0 + k];
    }
    __syncthreads();
#pragma unroll 8
    for (int k = 0; k < 64; ++k) {
      const float a = A[t][k];
#pragma unroll
      for (int n = 0; n < 19; ++n) acc[n] = fmaf(a, WL[k][n], acc[n]);
    }
  }
  const int g = g0 + t;
  const int b = g >> 12, pin = g & 4095;
#pragma unroll
  for (int n = 0; n < 19; ++n)
    O[((size_t)(b * 19 + n)) * 4096 + pin] = acc[n] + B4[n];
}

// ---------- 3x3 conv, 2-PRODUCT split-bf16 (ah*bh + ah*bl), hi-only A ----------
// 1024 thr = 16 waves (4M x 4N), wave tile 64x32. A HI plane only in LDS
// (2 x 24KB dbuf -> 48KB, 2-block-capable), B hi+lo via global->register.
// Per tap per wave: 4 ds_read_b128 + 4 B gloads + 8 MFMA. One barrier per cs.
// CM = channel-block byte multiplier in A (32 for [px][2048] X2, 64 for
// legacy packed oB2 whose hi plane sits at cb*64).
// A operand: row=lane&31, k=(lane>>5)*8+e. C/D: col=lane&31,
// row=(reg&3)+8*(reg>>2)+4*(lane>>5)  [m74/m101; validated R8-R17 absmax].
template <int AINIT>
__global__ __launch_bounds__(1024, 4) void conv9w2_k(
    const ushort_t* __restrict__ A1, int S1, int CM,
    const ushort_t* __restrict__ WB, int CBt, int cbOff,
    const ushort_t* __restrict__ zp,
    float* __restrict__ Co) {
  constexpr int RW = 6;
  constexpr int SLOTS = 24;        // (pxb 0..11) x (kk 0..1), 1KB each
  constexpr int ABUF = 24576;
  __shared__ char Ald[2 * ABUF];   // 48KB
  const int t = threadIdx.x, lane = t & 63, wid = t >> 6;  // wid 0..15
  const int wr = wid >> 2;   // 0..3 (M)
  const int wcn = wid & 3;   // 0..3 (N)
  const int gid = blockIdx.x, xcd = gid & 7, k_ = gid >> 3;
  const int by = xcd * 8 + (k_ & 7), bx = k_ >> 3;
  const int b = by >> 4, r0 = (by & 15) * 4, bbase = b * 4096;
  const int pxl = lane & 31;
  const int khalf = lane >> 5;
  const int lofs = lane * 16;
  const int row0 = by * 256 + wr * 64;
  const int col0 = bx * 128 + wcn * 32;
  const int rb = 4 * khalf;
  const int cg = bx * 4 + wcn;

  auto stageAslice = [&](int cb, int bufA, int i) {
    const int g = wid + i * 16;
    if (g < SLOTS) {
      const int pxb = g >> 1, kk = g & 1;
      const int p = pxb * 32 + pxl;
      const int irow = r0 + (p >> 6) - 1;
      const int gpx = bbase + irow * 64 + (p & 63);
      const ulong_t el = (ulong_t)gpx * (uint_t)S1 +
                         (uint_t)(cb * CM + (kk * 2 + khalf) * 8);
      const bool oob = (unsigned)irow >= 64u;
      const ulong_t src = oob ? (ulong_t)(zp + lane * 8) : (ulong_t)(A1 + el);
      gload16(src, Ald + bufA + g * 1024);
    }
  };

  struct BS { bf16x8 b[2][2]; };  // [kk][dt]
  auto loadB = [&](BS& s, int cs, int tap) {
#pragma unroll
    for (int kk = 0; kk < 2; ++kk)
#pragma unroll
      for (int dt = 0; dt < 2; ++dt) {
        const size_t b16 =
            ((((size_t)((cs + cbOff) * 9 + tap) * 16 + cg) * 2 + dt) * 2 + kk) * 64 + lane;
        s.b[kk][dt] = *(const bf16x8*)(WB + b16 * 8);
      }
  };

  f32x16 acc[2];
  if constexpr (AINIT) {
#pragma unroll
    for (int mi = 0; mi < 2; ++mi) {
      const int c = col0 + pxl;
#pragma unroll
      for (int rg = 0; rg < 16; ++rg) {
        const int r = row0 + mi * 32 + (rg & 3) + 8 * (rg >> 2) + rb;
        acc[mi][rg] = Co[(size_t)r * 512 + c];
      }
    }
  } else {
    acc[0] = (f32x16){0.f};
    acc[1] = (f32x16){0.f};
  }

  // prologue: stage A(cs=0) into buf0
#pragma unroll
  for (int i = 0; i < 2; ++i) stageAslice(0, 0, i);
  WAITV(0);
  SB();
  __builtin_amdgcn_s_barrier();
  SB();

  for (int cs = 0; cs < CBt; ++cs) {
    const int ab = (cs & 1) * ABUF;
    const int nb = ((cs + 1) & 1) * ABUF;
#pragma unroll
    for (int tap = 0; tap < 9; ++tap) {
      BS wa;
      loadB(wa, cs, tap);  // latency hides under A ds_reads / other waves
      if (tap < 2 && cs + 1 < CBt) stageAslice(cs + 1, nb, tap);
      const int prow = wr + tap / 3, dx = tap % 3 - 1;
      const char* Ab = Ald + ab;
      bf16x8 a[2][2];  // [mi][kk], hi plane only
#pragma unroll
      for (int mi = 0; mi < 2; ++mi) {
        const int pb0 = prow * 2 + mi;
        int ao0;
        if (dx == 0) {
          ao0 = pb0 * 2048 + lofs;
        } else {
          int px = pb0 * 32 + pxl + dx;
          px = px < 0 ? 0 : (px > RW * 64 - 1 ? RW * 64 - 1 : px);  // masked lanes only
          ao0 = (px >> 5) * 2048 + khalf * 512 + (px & 31) * 16;
        }
#pragma unroll
        for (int kk = 0; kk < 2; ++kk)
          a[mi][kk] = *(const bf16x8*)(Ab + ao0 + kk * 1024);
      }
      if (dx == -1 && pxl == 0) { bf16x8 z = {}; a[0][0] = z; a[0][1] = z; }
      if (dx == 1 && pxl == 31) { bf16x8 z = {}; a[1][0] = z; a[1][1] = z; }
      __builtin_amdgcn_s_setprio(1);
#pragma unroll
      for (int kk = 0; kk < 2; ++kk) {
        acc[0] = __builtin_amdgcn_mfma_f32_32x32x16_bf16(a[0][kk], wa.b[kk][0], acc[0], 0, 0, 0);
        acc[1] = __builtin_amdgcn_mfma_f32_32x32x16_bf16(a[1][kk], wa.b[kk][0], acc[1], 0, 0, 0);
        acc[0] = __builtin_amdgcn_mfma_f32_32x32x16_bf16(a[0][kk], wa.b[kk][1], acc[0], 0, 0, 0);
        acc[1] = __builtin_amdgcn_mfma_f32_32x32x16_bf16(a[1][kk], wa.b[kk][1], acc[1], 0, 0, 0);
      }
      __builtin_amdgcn_s_setprio(0);
    }
    WAITV(0);
    SB();
    __builtin_amdgcn_s_barrier();
    SB();
  }

  // epilogue: C/D col=lane&31, row=(reg&3)+8*(reg>>2)+4*(lane>>5)
#pragma unroll
  for (int mi = 0; mi < 2; ++mi) {
    const int c = col0 + pxl;
#pragma unroll
    for (int rg = 0; rg < 16; ++rg) {
      const int r = row0 + mi * 32 + (rg & 3) + 8 * (rg >> 2) + rb;
      Co[(size_t)r * 512 + c] = acc[mi][rg];
    }
  }
}

// ---------- 1x1 conv (convb): legacy LDS-B 3-product path, EPI=bias+pack ----------
__global__ __launch_bounds__(512, 2) void conv1x1_k(
    const ushort_t* __restrict__ A1, int S1,
    const ushort_t* __restrict__ WB, int CBt, int NBS,
    const ushort_t* __restrict__ zp,
    ushort_t* __restrict__ Cp, const float* __restrict__ bias) {
  constexpr int SPD = 16;
  constexpr int AI = 4;
  constexpr int APL = 16384;
  constexpr int ABUF = 32768;
  __shared__ char lds_all[147456];
  char* Ald = lds_all;
  char* Bld = lds_all + 98304;
  const int t = threadIdx.x, lane = t & 63, wid = t >> 6;
  const int wr = wid >> 1, wc = wid & 1;
  const int gid = blockIdx.x, xcd = gid & 7, k_ = gid >> 3;
  const int by = xcd * 8 + (k_ & 7), bx = k_ >> 3;
  const int b = by >> 4, r0 = (by & 15) * 4, bbase = b * 4096;
  const int pxl = lane & 31;
  const int khalf = lane >> 5;
  const int lofs = lane * 16;

  auto stageA = [&](int cb, int bufA) {
#pragma unroll
    for (int i = 0; i < AI; ++i) {
      const int g = wid * AI + i;
      const int d = g / SPD, rem = g - d * SPD;
      const int pxb = rem >> 1, kk = rem & 1;
      const int p = pxb * 32 + pxl;
      const int irow = r0 + (p >> 6);
      const int gpx = bbase + irow * 64 + (p & 63);
      const ulong_t el = (ulong_t)gpx * (uint_t)S1 +
                         (uint_t)(cb * 64 + d * 32 + (kk * 2 + khalf) * 8);
      gload16((ulong_t)(A1 + el), Ald + bufA + d * APL + (pxb * 2 + kk) * 1024);
    }
  };
  auto stageB = [&](int cb, int bufB) {
#pragma unroll
    for (int q = 0; q < 2; ++q) {
      const int s = wid * 2 + q;
      const int d = s >> 3, rem = s & 7, cob = rem >> 1, kk = rem & 1;
      const int co = bx * 128 + cob * 32 + pxl;
      const ulong_t el = (ulong_t)co * (uint_t)NBS +
                         (uint_t)(cb * 64 + d * 32 + (kk * 2 + khalf) * 8);
      gload16((ulong_t)(WB + el), Bld + bufB + d * 8192 + (cob * 2 + kk) * 1024);
    }
  };

  f32x16 acc[2][2];
#pragma unroll
  for (int i = 0; i < 2; ++i)
#pragma unroll
    for (int j2 = 0; j2 < 2; ++j2) acc[i][j2] = (f32x16){0.f};

  auto compute = [&](int abufB, int bbufB) {
    const char* Ab = Ald + abufB;
    const char* Bb = Bld + bbufB;
    bf16x8 a[2][2][2], bf[2][2][2];
#pragma unroll
    for (int ni = 0; ni < 2; ++ni)
#pragma unroll
      for (int kk = 0; kk < 2; ++kk) {
        const int bo = (wc * 2 + ni) * 2048 + kk * 1024 + lofs;
        bf[ni][kk][0] = *(const bf16x8*)(Bb + bo);
        bf[ni][kk][1] = *(const bf16x8*)(Bb + 8192 + bo);
      }
#pragma unroll
    for (int mi = 0; mi < 2; ++mi) {
      const int ao0 = ((wr * 2 + mi)) * 2048 + lofs;
#pragma unroll
      for (int kk = 0; kk < 2; ++kk) {
        const int ao = ao0 + kk * 1024;
        a[mi][kk][0] = *(const bf16x8*)(Ab + ao);
        a[mi][kk][1] = *(const bf16x8*)(Ab + APL + ao);
      }
    }
#pragma unroll
    for (int kk = 0; kk < 2; ++kk) {
#pragma unroll
      for (int mi = 0; mi < 2; ++mi)
#pragma unroll
        for (int ni = 0; ni < 2; ++ni)
          acc[mi][ni] = __builtin_amdgcn_mfma_f32_32x32x16_bf16(
              a[mi][kk][0], bf[ni][kk][0], acc[mi][ni], 0, 0, 0);
#pragma unroll
      for (int mi = 0; mi < 2; ++mi)
#pragma unroll
        for (int ni = 0; ni < 2; ++ni)
          acc[mi][ni] = __builtin_amdgcn_mfma_f32_32x32x16_bf16(
              a[mi][kk][0], bf[ni][kk][1], acc[mi][ni], 0, 0, 0);
#pragma unroll
      for (int mi = 0; mi < 2; ++mi)
#pragma unroll
        for (int ni = 0; ni < 2; ++ni)
          acc[mi][ni] = __builtin_amdgcn_mfma_f32_32x32x16_bf16(
              a[mi][kk][1], bf[ni][kk][0], acc[mi][ni], 0, 0, 0);
    }
  };

  int rr = 0;
  stageA(0, 0);
  stageB(0, 0);
  SB();
  stageA(1, ABUF);
  stageB(1, 16384);
  for (int cs = 0; cs < CBt; ++cs) {
    SB();
    WAITV(6);
    SB();
    __builtin_amdgcn_s_barrier();
    SB();
    const int rr2 = nxt3(nxt3(rr));
    if (cs + 2 < CBt) {
      stageA(cs + 2, rr2 * ABUF);
      stageB(cs + 2, rr2 * 16384);
    }
    compute(rr * ABUF, rr * 16384);
    rr = nxt3(rr);
  }

  const int row0 = by * 256 + wr * 64;
  const int col0 = bx * 128 + wc * 64;
  const int rb = 4 * khalf;
#pragma unroll
  for (int ni = 0; ni < 2; ++ni) {
    const int c = col0 + ni * 32 + pxl;
    const float bv = bias[c];
    const size_t cg2 = (size_t)((c >> 5) << 6) + (c & 31);
#pragma unroll
    for (int mi = 0; mi < 2; ++mi)
#pragma unroll
      for (int rg = 0; rg < 16; ++rg) {
        const int r = row0 + mi * 32 + (rg & 3) + 8 * (rg >> 2) + rb;
        const float v = acc[mi][ni][rg] + bv;
        const ushort_t h = f2bf(v);
        Cp[(size_t)r * 1024 + cg2] = h;
        Cp[(size_t)r * 1024 + cg2 + 32] = f2bf(v - bf2f(h));
      }
  }
}

// ---------- host ----------
extern "C" void kernel_launch(void* const* d_in, const int* in_sizes, int n_in,
                              void* d_out, int out_size, void* d_ws, size_t ws_size,
                              hipStream_t stream) {
  const float* x  = (const float*)d_in[0];
  const float* Wa = (const float*)d_in[1];
  const float* ga = (const float*)d_in[2];
  const float* ba = (const float*)d_in[3];
  const float* Wb = (const float*)d_in[4];
  const float* bb = (const float*)d_in[5];
  const float* W1 = (const float*)d_in[6];
  const float* g1 = (const float*)d_in[7];
  const float* b1 = (const float*)d_in[8];
  const float* W4 = (const float*)d_in[9];
  const float* b4 = (const float*)d_in[10];
  float* out0 = (float*)d_out;
  float* outF = out0 + (size_t)4 * 512 * 64 * 64;

  char* ws = (char*)d_ws;
  size_t off = 0;
  auto take = [&](size_t bytes) -> char* {
    char* p = ws + off;
    off += (bytes + 255) & ~(size_t)255;
    return p;
  };
  const size_t PAD = 16384;
  ushort_t* zp  = (ushort_t*)take(8192);
  float* sumA = (float*)take(2048);
  float* ssA  = (float*)take(2048);
  float* scA  = (float*)take(2048);
  float* shA  = (float*)take(2048);
  float* sum1 = (float*)take(2048);
  float* ss1  = (float*)take(2048);
  float* sc1  = (float*)take(2048);
  float* sh1  = (float*)take(2048);
  ushort_t* X2  = (ushort_t*)take((size_t)16384 * 2048 * 2 + PAD);  // hi only
  ushort_t* WA2 = (ushort_t*)take((size_t)9 * 512 * 4096 * 2 + PAD);
  ushort_t* W12 = (ushort_t*)take((size_t)9 * 512 * 5120 * 2 + PAD);
  ushort_t* WBb = (ushort_t*)take((size_t)512 * 1024 * 2 + PAD);
  ushort_t* oA2 = (ushort_t*)take((size_t)16384 * 1024 * 2 + PAD);
  ushort_t* oB2 = (ushort_t*)take((size_t)16384 * 1024 * 2 + PAD);
  float* convaRaw = (float*)take((size_t)16384 * 512 * 4);
  float* conv1Raw = (float*)take((size_t)16384 * 512 * 4);
  if (ws_size < off) return;

  zero_k<<<dim3(24), dim3(256), 0, stream>>>((float*)ws, 6144);
  cvt_x2_k<<<dim3(256, 32), dim3(256), 0, stream>>>(x, X2);
  cvt_w3n_k<<<dim3(8, 512), dim3(256), 0, stream>>>(Wa, WA2, 2048, 512);
  cvt_w3n_k<<<dim3(10, 512), dim3(256), 0, stream>>>(W1, W12, 2560, 512);
  cvt_e_k<<<dim3(1024), dim3(256), 0, stream>>>(Wb, WBb);

  // conva: 3x3 over x (2-product)
  conv9w2_k<0><<<dim3(256), dim3(1024), 0, stream>>>(
      X2, 2048, 32, WA2, 64, 0, zp, convaRaw);

  // conv1a: 3x3 over x-channels (cb 0..63 of W12, 2-product)
  conv9w2_k<0><<<dim3(256), dim3(1024), 0, stream>>>(
      X2, 2048, 32, W12, 64, 0, zp, conv1Raw);

  stats_k<<<dim3(512), dim3(256), 0, stream>>>(convaRaw, sumA, ssA);
  bnparams_k<<<dim3(1), dim3(512), 0, stream>>>(sumA, ssA, ga, ba, scA, shA);
  bnact_k<<<dim3(2048), dim3(256), 0, stream>>>(convaRaw, scA, shA, oA2);

  // convb: 1x1 + bias (3-product legacy), packed bf16 hi/lo out
  conv1x1_k<<<dim3(256), dim3(512), 0, stream>>>(
      oA2, 1024, WBb, 16, 1024, zp, oB2, bb);

  // conv1b: 3x3 over oB channels (cb 64..79 of W12, 2-product; oB hi at cb*64)
  conv9w2_k<1><<<dim3(256), dim3(1024), 0, stream>>>(
      oB2, 1024, 64, W12, 16, 64, zp, conv1Raw);

  stats_k<<<dim3(512), dim3(256), 0, stream>>>(conv1Raw, sum1, ss1);
  bnparams_k<<<dim3(1), dim3(512), 0, stream>>>(sum1, ss1, g1, b1, sc1, sh1);

  bn_nchw_k<<<dim3(256, 8), dim3(256), 0, stream>>>(conv1Raw, sc1, sh1, out0);
  conv4_k<<<dim3(64), dim3(256), 0, stream>>>(conv1Raw, sc1, sh1, W4, b4, outF);
}